// Round 2
// baseline (565.035 us; speedup 1.0000x reference)
//
#include <hip/hip_runtime.h>
#include <hip/hip_bf16.h>

#define NH 12
constexpr float SCALE = 0.17677669529663687f;  // 1/sqrt(32)
constexpr int TOKENS = 100352;

using f32x4  = __attribute__((ext_vector_type(4))) float;
using bf16x8 = __attribute__((ext_vector_type(8))) __bf16;

__device__ inline void gload_lds16(const void* g, void* l) {
  __builtin_amdgcn_global_load_lds(
      (const __attribute__((address_space(1))) void*)g,
      (__attribute__((address_space(3))) void*)l, 16, 0, 0);
}

// ---------------- K0: weight bf16 conversion + transposed padded bias ----------
// biasTt layout: [12][64 col(j)][64 row(i)] fp32; j>=49 -> -1e30 (mask), i>=49 -> 0.
__global__ __launch_bounds__(256) void wa_prep(
    const float* __restrict__ qkv_w, const float* __restrict__ proj_w,
    const float* __restrict__ tbl,
    __bf16* __restrict__ qkv_w_bf, __bf16* __restrict__ proj_w_bf,
    float* __restrict__ biasTt) {
  int p = blockIdx.x * 256 + threadIdx.x;
  if (p < 442368) { qkv_w_bf[p] = (__bf16)qkv_w[p]; return; }
  p -= 442368;
  if (p < 147456) { proj_w_bf[p] = (__bf16)proj_w[p]; return; }
  p -= 147456;
  if (p >= 49152) return;
  int h = p >> 12, rem = p & 4095, j = rem >> 6, i = rem & 63;  // j=key col, i=query row
  float v;
  if (j >= 49) v = -1e30f;
  else if (i >= 49) v = 0.0f;
  else {
    int py = i / 7, px = i % 7, qy = j / 7, qx = j % 7;
    v = tbl[((py - qy + 6) * 13 + (px - qx + 6)) * NH + h];
  }
  biasTt[p] = v;
}

// ---------------- K1: QKV GEMM, A-resident (x read once) ----------------
// Block: 64 rows x full N=1152 (nb loop of 9). A fp32->bf16 staged once (swizzled).
// B: global_load_lds, source-preswizzled, BK=64. 4 waves = 2x2, wave tile 32x64.
__global__ __launch_bounds__(256, 2) void wa_qkv(
    const float* __restrict__ x, const __bf16* __restrict__ wq,
    const float* __restrict__ qkv_b, __bf16* __restrict__ qkv) {
  __shared__ __bf16 As[64 * 384];   // [row][slot^(row&7) within 8-groups]
  __shared__ __bf16 Bs[128 * 64];   // [c][slot ^ (c&7)] linear for gload_lds
  const int t = threadIdx.x, lane = t & 63, wv = t >> 6;
  const int lr = lane & 15, ls = lane >> 4;
  const int mb = blockIdx.x;
  const int wr = wv >> 1, wc = wv & 1;
  // stage A: 64 rows x 48 slots of 8 elems, fp32 -> bf16
  #pragma unroll
  for (int i = 0; i < 12; ++i) {
    int p = i * 256 + t;
    int row = p / 48, slot = p - row * 48;
    const float* src = x + (size_t)(mb * 64 + row) * 384 + slot * 8;
    float4 a = *(const float4*)src;
    float4 b = *(const float4*)(src + 4);
    bf16x8 o;
    o[0] = (__bf16)a.x; o[1] = (__bf16)a.y; o[2] = (__bf16)a.z; o[3] = (__bf16)a.w;
    o[4] = (__bf16)b.x; o[5] = (__bf16)b.y; o[6] = (__bf16)b.z; o[7] = (__bf16)b.w;
    int sw = (slot & ~7) | ((slot & 7) ^ (row & 7));
    *(bf16x8*)(As + row * 384 + sw * 8) = o;
  }
  for (int nb = 0; nb < 9; ++nb) {
    f32x4 acc[2][4] = {};
    for (int kk = 0; kk < 6; ++kk) {
      __syncthreads();  // prev-iter reads done (also covers A-stage on first iter)
      #pragma unroll
      for (int j = 0; j < 4; ++j) {  // stage 16KB B-tile
        int p = wv * 256 + j * 64 + lane;
        int c = p >> 3, sl = p & 7;
        int s = sl ^ (c & 7);
        gload_lds16(wq + (size_t)(nb * 128 + c) * 384 + kk * 64 + s * 8, Bs + p * 8);
      }
      __syncthreads();  // drains vmcnt(0): B ready
      #pragma unroll
      for (int ks = 0; ks < 2; ++ks) {
        bf16x8 af[2], bfr[4];
        #pragma unroll
        for (int rt = 0; rt < 2; ++rt) {
          int row = wr * 32 + rt * 16 + lr;
          int slot = kk * 8 + ks * 4 + ls;
          int sw = (slot & ~7) | ((slot & 7) ^ (row & 7));
          af[rt] = *(const bf16x8*)(As + row * 384 + sw * 8);
        }
        #pragma unroll
        for (int ct = 0; ct < 4; ++ct) {
          int c = wc * 64 + ct * 16 + lr;
          bfr[ct] = *(const bf16x8*)(Bs + (c * 8 + ((ks * 4 + ls) ^ (c & 7))) * 8);
        }
        #pragma unroll
        for (int rt = 0; rt < 2; ++rt)
          #pragma unroll
          for (int ct = 0; ct < 4; ++ct)
            acc[rt][ct] = __builtin_amdgcn_mfma_f32_16x16x32_bf16(af[rt], bfr[ct], acc[rt][ct], 0, 0, 0);
      }
    }
    // epilogue: + bias, bf16 scalar stores (wave's 4 ct cover 128B -> lines filled)
    #pragma unroll
    for (int ct = 0; ct < 4; ++ct) {
      int col = nb * 128 + wc * 64 + ct * 16 + lr;
      float b = qkv_b[col];
      #pragma unroll
      for (int rt = 0; rt < 2; ++rt)
        #pragma unroll
        for (int r = 0; r < 4; ++r) {
          int row = wr * 32 + rt * 16 + ls * 4 + r;
          qkv[(size_t)(mb * 64 + row) * 1152 + col] = (__bf16)(acc[rt][ct][r] + b);
        }
    }
  }
}

// ---------------- K2a: attention, one wave per (window, 3 heads) ----------------
// No inter-wave barriers. Softmax: no max-sub (bounded inputs), denom via ones-MFMA.
// H written into the Q-slice of qkv (owned by this (w,h), read-before-write).
__global__ __launch_bounds__(256, 3) void wa_attn(
    const float* __restrict__ biasTt, __bf16* __restrict__ qkv) {
  __shared__ __bf16 Pbuf[4][4096];
  const int t = threadIdx.x, lane = t & 63, wv = t >> 6;
  const int lr = lane & 15, ls = lane >> 4;
  const int w = blockIdx.x;
  const int w49 = w * 49;
  __bf16* Pw = Pbuf[wv];
  f32x4 zero = {0.f, 0.f, 0.f, 0.f};
  bf16x8 ones;
  #pragma unroll
  for (int e = 0; e < 8; ++e) ones[e] = (__bf16)1.0f;

  for (int hi = 0; hi < 3; ++hi) {
    const int h = wv + hi * 4;
    // Q,K fragments direct from global (full 64B cache lines per 16 rows)
    bf16x8 qa[4], kb[4];
    #pragma unroll
    for (int rt = 0; rt < 4; ++rt) {
      int tok = min(w49 + rt * 16 + lr, TOKENS - 1);
      qa[rt] = *(const bf16x8*)(qkv + (size_t)tok * 1152 + h * 32 + ls * 8);
    }
    #pragma unroll
    for (int ct = 0; ct < 4; ++ct) {
      int tok = min(w49 + ct * 16 + lr, TOKENS - 1);
      kb[ct] = *(const bf16x8*)(qkv + (size_t)tok * 1152 + 384 + h * 32 + ls * 8);
    }
    f32x4 sacc[4][4];
    #pragma unroll
    for (int rt = 0; rt < 4; ++rt)
      #pragma unroll
      for (int ct = 0; ct < 4; ++ct)
        sacc[rt][ct] = __builtin_amdgcn_mfma_f32_16x16x32_bf16(qa[rt], kb[ct], zero, 0, 0, 0);
    // scale + bias + exp -> swizzled Pbuf (unnormalized probs; masked cols -> 0)
    #pragma unroll
    for (int rt = 0; rt < 4; ++rt) {
      int row0 = rt * 16 + ls * 4;
      #pragma unroll
      for (int ct = 0; ct < 4; ++ct) {
        int col = ct * 16 + lr;
        float4 bias = *(const float4*)(biasTt + (size_t)(h * 64 + col) * 64 + row0);
        #pragma unroll
        for (int r = 0; r < 4; ++r) {
          int row = row0 + r;
          float pr = __expf(fmaf(sacc[rt][ct][r], SCALE, ((const float*)&bias)[r]));
          Pw[row * 64 + (((col >> 3) ^ (row & 7)) * 8) + (col & 7)] = (__bf16)pr;
        }
      }
    }
    // PV + row sums (ones column trick): V^T frags via scalar loads (32B runs/instr)
    f32x4 oacc[4][2] = {};
    f32x4 osum[4] = {zero, zero, zero, zero};
    #pragma unroll
    for (int ks = 0; ks < 2; ++ks) {
      bf16x8 vb0, vb1;
      #pragma unroll
      for (int e = 0; e < 8; ++e) {
        int tok = min(w49 + ks * 32 + ls * 8 + e, TOKENS - 1);
        const __bf16* vp = qkv + (size_t)tok * 1152 + 768 + h * 32 + lr;
        vb0[e] = vp[0];
        vb1[e] = vp[16];
      }
      #pragma unroll
      for (int rt = 0; rt < 4; ++rt) {
        int row = rt * 16 + lr;
        bf16x8 pa = *(const bf16x8*)(Pw + row * 64 + (((ks * 4 + ls) ^ (row & 7)) * 8));
        oacc[rt][0] = __builtin_amdgcn_mfma_f32_16x16x32_bf16(pa, vb0, oacc[rt][0], 0, 0, 0);
        oacc[rt][1] = __builtin_amdgcn_mfma_f32_16x16x32_bf16(pa, vb1, oacc[rt][1], 0, 0, 0);
        osum[rt]    = __builtin_amdgcn_mfma_f32_16x16x32_bf16(pa, ones, osum[rt], 0, 0, 0);
      }
    }
    // normalize + write H into Q slice (rows < 49 only)
    #pragma unroll
    for (int rt = 0; rt < 4; ++rt)
      #pragma unroll
      for (int r = 0; r < 4; ++r) {
        int row = rt * 16 + ls * 4 + r;
        if (row < 49) {
          float inv = 1.0f / osum[rt][r];
          __bf16* o = qkv + (size_t)(w49 + row) * 1152 + h * 32;
          o[lr]      = (__bf16)(oacc[rt][0][r] * inv);
          o[16 + lr] = (__bf16)(oacc[rt][1][r] * inv);
        }
      }
  }
}

// ---------------- K2b: proj GEMM  out = H @ proj_w^T + proj_b (fp32 out) --------
// Same structure as K1; A (=H, bf16 in qkv cols 0..383) staged via gload_lds.
__global__ __launch_bounds__(256, 2) void wa_proj(
    const __bf16* __restrict__ qkv, const __bf16* __restrict__ pw,
    const float* __restrict__ proj_b, float* __restrict__ out) {
  __shared__ __bf16 As[64 * 384];
  __shared__ __bf16 Bs[128 * 64];
  const int t = threadIdx.x, lane = t & 63, wv = t >> 6;
  const int lr = lane & 15, ls = lane >> 4;
  const int mb = blockIdx.x;
  const int wr = wv >> 1, wc = wv & 1;
  // stage A via gload_lds: linear dest, source pre-swizzled, stride 1152
  #pragma unroll
  for (int j = 0; j < 12; ++j) {
    int p = wv * 768 + j * 64 + lane;
    int row = p / 48, sl = p - row * 48;
    int s = (sl & ~7) | ((sl & 7) ^ (row & 7));
    gload_lds16(qkv + (size_t)(mb * 64 + row) * 1152 + s * 8, As + p * 8);
  }
  for (int nb = 0; nb < 3; ++nb) {
    f32x4 acc[2][4] = {};
    for (int kk = 0; kk < 6; ++kk) {
      __syncthreads();
      #pragma unroll
      for (int j = 0; j < 4; ++j) {
        int p = wv * 256 + j * 64 + lane;
        int c = p >> 3, sl = p & 7;
        int s = sl ^ (c & 7);
        gload_lds16(pw + (size_t)(nb * 128 + c) * 384 + kk * 64 + s * 8, Bs + p * 8);
      }
      __syncthreads();
      #pragma unroll
      for (int ks = 0; ks < 2; ++ks) {
        bf16x8 af[2], bfr[4];
        #pragma unroll
        for (int rt = 0; rt < 2; ++rt) {
          int row = wr * 32 + rt * 16 + lr;
          int slot = kk * 8 + ks * 4 + ls;
          int sw = (slot & ~7) | ((slot & 7) ^ (row & 7));
          af[rt] = *(const bf16x8*)(As + row * 384 + sw * 8);
        }
        #pragma unroll
        for (int ct = 0; ct < 4; ++ct) {
          int c = wc * 64 + ct * 16 + lr;
          bfr[ct] = *(const bf16x8*)(Bs + (c * 8 + ((ks * 4 + ls) ^ (c & 7))) * 8);
        }
        #pragma unroll
        for (int rt = 0; rt < 2; ++rt)
          #pragma unroll
          for (int ct = 0; ct < 4; ++ct)
            acc[rt][ct] = __builtin_amdgcn_mfma_f32_16x16x32_bf16(af[rt], bfr[ct], acc[rt][ct], 0, 0, 0);
      }
    }
    // epilogue: fp32 coalesced stores + bias
    #pragma unroll
    for (int ct = 0; ct < 4; ++ct) {
      int col = nb * 128 + wc * 64 + ct * 16 + lr;
      float b = proj_b[col];
      #pragma unroll
      for (int rt = 0; rt < 2; ++rt)
        #pragma unroll
        for (int r = 0; r < 4; ++r) {
          int row = wr * 32 + rt * 16 + ls * 4 + r;
          out[(size_t)(mb * 64 + row) * 384 + col] = acc[rt][ct][r] + b;
        }
    }
  }
}

extern "C" void kernel_launch(void* const* d_in, const int* in_sizes, int n_in,
                              void* d_out, int out_size, void* d_ws, size_t ws_size,
                              hipStream_t stream) {
  const float* x      = (const float*)d_in[0];
  const float* qkv_w  = (const float*)d_in[1];
  const float* qkv_b  = (const float*)d_in[2];
  const float* proj_w = (const float*)d_in[3];
  const float* proj_b = (const float*)d_in[4];
  const float* tbl    = (const float*)d_in[5];
  float* out = (float*)d_out;

  char* ws = (char*)d_ws;
  __bf16* qkv_w_bf  = (__bf16*)ws;                  // 884,736 B
  __bf16* proj_w_bf = (__bf16*)(ws + 884736);       // 294,912 B
  float*  biasTt    = (float*)(ws + 1179648);       // 196,608 B
  __bf16* qkv_buf   = (__bf16*)(ws + 1376256);      // 231,211,008 B

  wa_prep<<<2496, 256, 0, stream>>>(qkv_w, proj_w, tbl, qkv_w_bf, proj_w_bf, biasTt);
  wa_qkv<<<1568, 256, 0, stream>>>(x, qkv_w_bf, qkv_b, qkv_buf);
  wa_attn<<<2048, 256, 0, stream>>>(biasTt, qkv_buf);
  wa_proj<<<1568, 256, 0, stream>>>(qkv_buf, proj_w_bf, proj_b, out);
}

// Round 3
// 389.132 us; speedup vs baseline: 1.4520x; 1.4520x over previous
//
#include <hip/hip_runtime.h>
#include <hip/hip_bf16.h>

#define NH 12
constexpr float SCALE = 0.17677669529663687f;  // 1/sqrt(32)
constexpr int TOKENS = 100352;

using f32x4  = __attribute__((ext_vector_type(4))) float;
using bf16x8 = __attribute__((ext_vector_type(8))) __bf16;

__device__ inline void gload_lds16(const void* g, void* l) {
  __builtin_amdgcn_global_load_lds(
      (const __attribute__((address_space(1))) void*)g,
      (__attribute__((address_space(3))) void*)l, 16, 0, 0);
}

// ---------------- K0: weight bf16 conversion + transposed padded bias ----------
// biasTt layout: [12][64 col(j)][64 row(i)] fp32; j>=49 -> -1e30 (mask), i>=49 -> 0.
__global__ __launch_bounds__(256) void wa_prep(
    const float* __restrict__ qkv_w, const float* __restrict__ proj_w,
    const float* __restrict__ tbl,
    __bf16* __restrict__ qkv_w_bf, __bf16* __restrict__ proj_w_bf,
    float* __restrict__ biasTt) {
  int p = blockIdx.x * 256 + threadIdx.x;
  if (p < 442368) { qkv_w_bf[p] = (__bf16)qkv_w[p]; return; }
  p -= 442368;
  if (p < 147456) { proj_w_bf[p] = (__bf16)proj_w[p]; return; }
  p -= 147456;
  if (p >= 49152) return;
  int h = p >> 12, rem = p & 4095, j = rem >> 6, i = rem & 63;  // j=key col, i=query row
  float v;
  if (j >= 49) v = -1e30f;
  else if (i >= 49) v = 0.0f;
  else {
    int py = i / 7, px = i % 7, qy = j / 7, qx = j % 7;
    v = tbl[((py - qy + 6) * 13 + (px - qx + 6)) * NH + h];
  }
  biasTt[p] = v;
}

// ---------------- K1: QKV GEMM, A-resident, 2-phase pipelined ----------------
// Block: 64 rows x full N=1152 (nb loop of 9). A fp32->bf16 staged once (swizzled).
// B: global_load_lds double-buffered; STAGE(t+1) issued before compute(t);
// ONE barrier per K-step. 4 waves = 2x2, wave tile 32x64.
__global__ __launch_bounds__(256, 2) void wa_qkv(
    const float* __restrict__ x, const __bf16* __restrict__ wq,
    const float* __restrict__ qkv_b, __bf16* __restrict__ qkv) {
  __shared__ __bf16 As[64 * 384];      // 48KB, [row][slot^(row&7) per 8-group]
  __shared__ __bf16 Bs[2][128 * 64];   // 2 x 16KB, [c][slot ^ (c&7)] linear
  const int t = threadIdx.x, lane = t & 63, wv = t >> 6;
  const int lr = lane & 15, ls = lane >> 4;
  const int mb = blockIdx.x;
  const int wr = wv >> 1, wc = wv & 1;
  // stage A: 64 rows x 48 slots of 8 elems, fp32 -> bf16
  #pragma unroll
  for (int i = 0; i < 12; ++i) {
    int p = i * 256 + t;
    int row = p / 48, slot = p - row * 48;
    const float* src = x + (size_t)(mb * 64 + row) * 384 + slot * 8;
    float4 a = *(const float4*)src;
    float4 b = *(const float4*)(src + 4);
    bf16x8 o;
    o[0] = (__bf16)a.x; o[1] = (__bf16)a.y; o[2] = (__bf16)a.z; o[3] = (__bf16)a.w;
    o[4] = (__bf16)b.x; o[5] = (__bf16)b.y; o[6] = (__bf16)b.z; o[7] = (__bf16)b.w;
    int sw = (slot & ~7) | ((slot & 7) ^ (row & 7));
    *(bf16x8*)(As + row * 384 + sw * 8) = o;
  }
  // stage B tile for step st into buffer bp
  auto stage_b = [&](int st, int bp) {
    int nb = st / 6, kk = st - nb * 6;
    #pragma unroll
    for (int j = 0; j < 4; ++j) {
      int p = wv * 256 + j * 64 + lane;
      int c = p >> 3, sl = p & 7;
      int s = sl ^ (c & 7);
      gload_lds16(wq + (size_t)(nb * 128 + c) * 384 + kk * 64 + s * 8, Bs[bp] + p * 8);
    }
  };
  stage_b(0, 0);
  __syncthreads();
  for (int nb = 0; nb < 9; ++nb) {
    f32x4 acc[2][4] = {};
    for (int kk = 0; kk < 6; ++kk) {
      int st = nb * 6 + kk;
      if (st < 53) stage_b(st + 1, (st + 1) & 1);
      const __bf16* B = Bs[st & 1];
      #pragma unroll
      for (int ks = 0; ks < 2; ++ks) {
        bf16x8 af[2], bfr[4];
        #pragma unroll
        for (int rt = 0; rt < 2; ++rt) {
          int row = wr * 32 + rt * 16 + lr;
          int slot = kk * 8 + ks * 4 + ls;
          int sw = (slot & ~7) | ((slot & 7) ^ (row & 7));
          af[rt] = *(const bf16x8*)(As + row * 384 + sw * 8);
        }
        #pragma unroll
        for (int ct = 0; ct < 4; ++ct) {
          int c = wc * 64 + ct * 16 + lr;
          bfr[ct] = *(const bf16x8*)(B + (c * 8 + ((ks * 4 + ls) ^ (c & 7))) * 8);
        }
        #pragma unroll
        for (int rt = 0; rt < 2; ++rt)
          #pragma unroll
          for (int ct = 0; ct < 4; ++ct)
            acc[rt][ct] = __builtin_amdgcn_mfma_f32_16x16x32_bf16(af[rt], bfr[ct], acc[rt][ct], 0, 0, 0);
      }
      __syncthreads();  // drains stage(st+1) + orders buffer reuse
    }
    // epilogue: + bias; the two 32B halves of each 64B sector stored back-to-back
    float bias[4];
    #pragma unroll
    for (int ct = 0; ct < 4; ++ct) bias[ct] = qkv_b[nb * 128 + wc * 64 + ct * 16 + lr];
    #pragma unroll
    for (int rt = 0; rt < 2; ++rt)
      #pragma unroll
      for (int r = 0; r < 4; ++r) {
        int row = wr * 32 + rt * 16 + ls * 4 + r;
        __bf16* dst = qkv + (size_t)(mb * 64 + row) * 1152 + nb * 128 + wc * 64;
        #pragma unroll
        for (int ct = 0; ct < 4; ++ct)
          dst[ct * 16 + lr] = (__bf16)(acc[rt][ct][r] + bias[ct]);
      }
  }
}

// ---------------- K2a: attention, one wave per (window, head) ----------------
// 24576 independent waves, no barriers. V staged in wave-private LDS (vector
// loads, chunk-XOR swizzle). Softmax: no max-sub (bounded), denom via ones-MFMA.
// H written into the Q-slice of qkv (owned by this (w,h)).
__global__ __launch_bounds__(256, 3) void wa_attn(
    const float* __restrict__ biasTt, __bf16* __restrict__ qkv) {
  __shared__ __bf16 Pbuf[4][4096];  // 8KB/wave
  __shared__ __bf16 Vbuf[4][2048];  // 4KB/wave
  const int t = threadIdx.x, lane = t & 63, wv = t >> 6;
  const int lr = lane & 15, ls = lane >> 4;
  const int pair = blockIdx.x * 4 + wv;     // 0..24575
  const int w = pair / NH, h = pair - w * NH;
  const int w49 = w * 49;
  __bf16* Pw = Pbuf[wv];
  __bf16* Vw = Vbuf[wv];
  f32x4 zero = {0.f, 0.f, 0.f, 0.f};
  bf16x8 ones;
  #pragma unroll
  for (int e = 0; e < 8; ++e) ones[e] = (__bf16)1.0f;

  // stage V: lane = row j (rows>=49 clamp to 48: finite, killed by P=0)
  {
    int row = lane;
    int tok = w49 + (row < 49 ? row : 48);
    const bf16x8* vsrc = (const bf16x8*)(qkv + (size_t)tok * 1152 + 768 + h * 32);
    int f = (row & 3) ^ ((row >> 3) & 3);
    #pragma unroll
    for (int c = 0; c < 4; ++c)
      *(bf16x8*)(Vw + row * 32 + ((c ^ f) * 8)) = vsrc[c];
  }
  // Q,K fragments direct from global (full 64B lines per 16 rows)
  bf16x8 qa[4], kb[4];
  #pragma unroll
  for (int rt = 0; rt < 4; ++rt) {
    int tok = min(w49 + rt * 16 + lr, TOKENS - 1);
    qa[rt] = *(const bf16x8*)(qkv + (size_t)tok * 1152 + h * 32 + ls * 8);
  }
  #pragma unroll
  for (int ct = 0; ct < 4; ++ct) {
    int tok = min(w49 + ct * 16 + lr, TOKENS - 1);
    kb[ct] = *(const bf16x8*)(qkv + (size_t)tok * 1152 + 384 + h * 32 + ls * 8);
  }
  f32x4 sacc[4][4];
  #pragma unroll
  for (int rt = 0; rt < 4; ++rt)
    #pragma unroll
    for (int ct = 0; ct < 4; ++ct)
      sacc[rt][ct] = __builtin_amdgcn_mfma_f32_16x16x32_bf16(qa[rt], kb[ct], zero, 0, 0, 0);
  // scale + bias + exp -> swizzled Pbuf (unnormalized probs; masked cols -> 0)
  #pragma unroll
  for (int rt = 0; rt < 4; ++rt) {
    int row0 = rt * 16 + ls * 4;
    #pragma unroll
    for (int ct = 0; ct < 4; ++ct) {
      int col = ct * 16 + lr;
      float4 bias = *(const float4*)(biasTt + (size_t)(h * 64 + col) * 64 + row0);
      #pragma unroll
      for (int r = 0; r < 4; ++r) {
        int row = row0 + r;
        float pr = __expf(fmaf(sacc[rt][ct][r], SCALE, ((const float*)&bias)[r]));
        Pw[row * 64 + (((col >> 3) ^ (row & 7)) * 8) + (col & 7)] = (__bf16)pr;
      }
    }
  }
  // PV + row sums (ones trick); V^T frags from LDS (swizzled scalar reads)
  f32x4 oacc[4][2] = {};
  f32x4 osum[4] = {zero, zero, zero, zero};
  #pragma unroll
  for (int ks = 0; ks < 2; ++ks) {
    bf16x8 vb0, vb1;
    #pragma unroll
    for (int e = 0; e < 8; ++e) {
      int j = ks * 32 + ls * 8 + e;
      int a = j * 32 + (((lr >> 3) ^ (e & 3) ^ ls) * 8) + (lr & 7);
      vb0[e] = Vw[a];
      vb1[e] = Vw[a ^ 16];
    }
    #pragma unroll
    for (int rt = 0; rt < 4; ++rt) {
      int row = rt * 16 + lr;
      bf16x8 pa = *(const bf16x8*)(Pw + row * 64 + (((ks * 4 + ls) ^ (row & 7)) * 8));
      oacc[rt][0] = __builtin_amdgcn_mfma_f32_16x16x32_bf16(pa, vb0, oacc[rt][0], 0, 0, 0);
      oacc[rt][1] = __builtin_amdgcn_mfma_f32_16x16x32_bf16(pa, vb1, oacc[rt][1], 0, 0, 0);
      osum[rt]    = __builtin_amdgcn_mfma_f32_16x16x32_bf16(pa, ones, osum[rt], 0, 0, 0);
    }
  }
  // normalize + write H into Q slice (rows < 49 only)
  #pragma unroll
  for (int rt = 0; rt < 4; ++rt)
    #pragma unroll
    for (int r = 0; r < 4; ++r) {
      int row = rt * 16 + ls * 4 + r;
      if (row < 49) {
        float inv = 1.0f / osum[rt][r];
        __bf16* o = qkv + (size_t)(w49 + row) * 1152 + h * 32;
        o[lr]      = (__bf16)(oacc[rt][0][r] * inv);
        o[16 + lr] = (__bf16)(oacc[rt][1][r] * inv);
      }
    }
}

// ---------------- K2b: proj GEMM, 2-phase pipelined ----------------
// out = H @ proj_w^T + proj_b (fp32 out). A (=H, bf16 in qkv cols 0..383)
// staged once via gload_lds; B double-buffered, 1 barrier/step.
__global__ __launch_bounds__(256, 2) void wa_proj(
    const __bf16* __restrict__ qkv, const __bf16* __restrict__ pw,
    const float* __restrict__ proj_b, float* __restrict__ out) {
  __shared__ __bf16 As[64 * 384];
  __shared__ __bf16 Bs[2][128 * 64];
  const int t = threadIdx.x, lane = t & 63, wv = t >> 6;
  const int lr = lane & 15, ls = lane >> 4;
  const int mb = blockIdx.x;
  const int wr = wv >> 1, wc = wv & 1;
  // stage A via gload_lds: linear dest, source pre-swizzled, stride 1152
  #pragma unroll
  for (int j = 0; j < 12; ++j) {
    int p = wv * 768 + j * 64 + lane;
    int row = p / 48, sl = p - row * 48;
    int s = (sl & ~7) | ((sl & 7) ^ (row & 7));
    gload_lds16(qkv + (size_t)(mb * 64 + row) * 1152 + s * 8, As + p * 8);
  }
  auto stage_b = [&](int st, int bp) {
    int nb = st / 6, kk = st - nb * 6;
    #pragma unroll
    for (int j = 0; j < 4; ++j) {
      int p = wv * 256 + j * 64 + lane;
      int c = p >> 3, sl = p & 7;
      int s = sl ^ (c & 7);
      gload_lds16(pw + (size_t)(nb * 128 + c) * 384 + kk * 64 + s * 8, Bs[bp] + p * 8);
    }
  };
  stage_b(0, 0);
  __syncthreads();
  for (int nb = 0; nb < 3; ++nb) {
    f32x4 acc[2][4] = {};
    for (int kk = 0; kk < 6; ++kk) {
      int st = nb * 6 + kk;
      if (st < 17) stage_b(st + 1, (st + 1) & 1);
      const __bf16* B = Bs[st & 1];
      #pragma unroll
      for (int ks = 0; ks < 2; ++ks) {
        bf16x8 af[2], bfr[4];
        #pragma unroll
        for (int rt = 0; rt < 2; ++rt) {
          int row = wr * 32 + rt * 16 + lr;
          int slot = kk * 8 + ks * 4 + ls;
          int sw = (slot & ~7) | ((slot & 7) ^ (row & 7));
          af[rt] = *(const bf16x8*)(As + row * 384 + sw * 8);
        }
        #pragma unroll
        for (int ct = 0; ct < 4; ++ct) {
          int c = wc * 64 + ct * 16 + lr;
          bfr[ct] = *(const bf16x8*)(B + (c * 8 + ((ks * 4 + ls) ^ (c & 7))) * 8);
        }
        #pragma unroll
        for (int rt = 0; rt < 2; ++rt)
          #pragma unroll
          for (int ct = 0; ct < 4; ++ct)
            acc[rt][ct] = __builtin_amdgcn_mfma_f32_16x16x32_bf16(af[rt], bfr[ct], acc[rt][ct], 0, 0, 0);
      }
      __syncthreads();
    }
    // epilogue: fp32 stores (full 64B line per instr) + bias
    #pragma unroll
    for (int ct = 0; ct < 4; ++ct) {
      int col = nb * 128 + wc * 64 + ct * 16 + lr;
      float b = proj_b[col];
      #pragma unroll
      for (int rt = 0; rt < 2; ++rt)
        #pragma unroll
        for (int r = 0; r < 4; ++r) {
          int row = wr * 32 + rt * 16 + ls * 4 + r;
          out[(size_t)(mb * 64 + row) * 384 + col] = acc[rt][ct][r] + b;
        }
    }
  }
}

extern "C" void kernel_launch(void* const* d_in, const int* in_sizes, int n_in,
                              void* d_out, int out_size, void* d_ws, size_t ws_size,
                              hipStream_t stream) {
  const float* x      = (const float*)d_in[0];
  const float* qkv_w  = (const float*)d_in[1];
  const float* qkv_b  = (const float*)d_in[2];
  const float* proj_w = (const float*)d_in[3];
  const float* proj_b = (const float*)d_in[4];
  const float* tbl    = (const float*)d_in[5];
  float* out = (float*)d_out;

  char* ws = (char*)d_ws;
  __bf16* qkv_w_bf  = (__bf16*)ws;                  // 884,736 B
  __bf16* proj_w_bf = (__bf16*)(ws + 884736);       // 294,912 B
  float*  biasTt    = (float*)(ws + 1179648);       // 196,608 B
  __bf16* qkv_buf   = (__bf16*)(ws + 1376256);      // 231,211,008 B

  wa_prep<<<2496, 256, 0, stream>>>(qkv_w, proj_w, tbl, qkv_w_bf, proj_w_bf, biasTt);
  wa_qkv<<<1568, 256, 0, stream>>>(x, qkv_w_bf, qkv_b, qkv_buf);
  wa_attn<<<6144, 256, 0, stream>>>(biasTt, qkv_buf);
  wa_proj<<<1568, 256, 0, stream>>>(qkv_buf, proj_w_bf, proj_b, out);
}